// Round 5
// baseline (1551.369 us; speedup 1.0000x reference)
//
#include <hip/hip_runtime.h>

// ---------------------------------------------------------------------------
// SubModel_22016002359901: 3x GCN(2 conv) + FC heads, N=100000, F=128, E=1.6M
// Round 5: bucketed CSR build. Edges partitioned into 196 buckets of 512
// dst-nodes (LDS histogram + per-(block,bucket) cursor atomic: 76K atomics vs
// 3.2M), then per-bucket LDS counting sort emits the sorted edge array
// coalesced AND computes deg/dinv/rp sequentially (no weighted-degree atomic
// pass at all). gather_bf / gemm_bf unchanged from round 4.
// ---------------------------------------------------------------------------

typedef short bf16x8 __attribute__((ext_vector_type(8)));
typedef float f32x4 __attribute__((ext_vector_type(4)));

#define NBUCK 196        // ceil(100000 / 512)
#define BSHIFT 9         // 512 nodes per bucket
#define BCAP 12288       // bucket capacity (avg 8163, sigma ~90 -> 45 sigma headroom)

static __device__ __forceinline__ float frelu(float x) { return x > 0.f ? x : 0.f; }

static __device__ __forceinline__ unsigned short f2bf(float f) {
    unsigned int u = __float_as_uint(f);
    u += 0x7fffu + ((u >> 16) & 1u);           // RNE
    return (unsigned short)(u >> 16);
}
static __device__ __forceinline__ float bflo(unsigned int u) {
    return __uint_as_float(u << 16);
}
static __device__ __forceinline__ float bfhi(unsigned int u) {
    return __uint_as_float(u & 0xffff0000u);
}

// ---------------- conversion kernels ----------------
__global__ void xconv(const float* __restrict__ src, unsigned short* __restrict__ dst, int n4) {
    int i = blockIdx.x * 256 + threadIdx.x;
    if (i >= n4) return;
    float4 v = *(const float4*)(src + (size_t)i * 4);
    ushort4 o = {f2bf(v.x), f2bf(v.y), f2bf(v.z), f2bf(v.w)};
    *(ushort4*)(dst + (size_t)i * 4) = o;
}

__global__ void wtrans(const float* __restrict__ src, unsigned short* __restrict__ dst,
                       int K, int M) {
    int i = blockIdx.x * 256 + threadIdx.x;
    if (i >= K * M) return;
    int m = i / K, k = i % K;
    dst[i] = f2bf(src[(size_t)k * M + m]);
}

// ---------------- bucketed CSR build ----------------
__global__ void zero_small(int* __restrict__ p, int n) {
    int i = blockIdx.x * 256 + threadIdx.x;
    if (i < n) p[i] = 0;
}

// partition edges into buckets by dst>>9; record = {src | dstlocal<<17, ew}
__global__ __launch_bounds__(256) void part_k(
    const int* __restrict__ src, const int* __restrict__ dst,
    const float* __restrict__ ew, int* __restrict__ gcur,
    int2* __restrict__ part, int nE) {
    __shared__ int lh[NBUCK];
    __shared__ int gb[NBUCK];
    const int tid = threadIdx.x;
    for (int t = tid; t < NBUCK; t += 256) lh[t] = 0;
    __syncthreads();
    const int e0 = blockIdx.x * 4096;
    int rk[16], bk[16];
#pragma unroll
    for (int j = 0; j < 16; ++j) {
        int e = e0 + j * 256 + tid;
        rk[j] = -1;
        if (e < nE) {
            int b = dst[e] >> BSHIFT;
            bk[j] = b;
            rk[j] = atomicAdd(&lh[b], 1);
        }
    }
    __syncthreads();
    for (int t = tid; t < NBUCK; t += 256)
        gb[t] = lh[t] ? atomicAdd(&gcur[t], lh[t]) : 0;
    __syncthreads();
#pragma unroll
    for (int j = 0; j < 16; ++j) {
        int e = e0 + j * 256 + tid;
        if (e >= nE) continue;
        int b = bk[j];
        int slot = gb[b] + rk[j];
        if (slot < BCAP) {
            int s = src[e];
            int dl = dst[e] & ((1 << BSHIFT) - 1);
            part[(size_t)b * BCAP + slot] = make_int2(s | (dl << 17), __float_as_int(ew[e]));
        }
    }
}

// exclusive scan of gcur[NBUCK] -> base[NBUCK]; rp[n] = E
__global__ void scanB(const int* __restrict__ gcur, int* __restrict__ base,
                      int* __restrict__ rp, int n, int E) {
    __shared__ int s[256];
    int t = threadIdx.x;
    int v = (t < NBUCK) ? gcur[t] : 0;
    s[t] = v;
    __syncthreads();
#pragma unroll
    for (int off = 1; off < 256; off <<= 1) {
        int x = (t >= off) ? s[t - off] : 0;
        __syncthreads();
        s[t] += x;
        __syncthreads();
    }
    if (t < NBUCK) base[t] = s[t] - v;
    if (t == 0) rp[n] = E;
}

// one workgroup per bucket: LDS counting sort by dstlocal, coalesced CSR emit,
// sequential deg sum -> dinv, rp.
__global__ __launch_bounds__(1024) void sort_k(
    const int2* __restrict__ part, const int* __restrict__ gcur,
    const int* __restrict__ base, int2* __restrict__ ev,
    int* __restrict__ rp, float* __restrict__ dinv, int n) {
    __shared__ int hist[512];
    __shared__ int cur[512];
    const int b = blockIdx.x;
    const int t = threadIdx.x;
    int cnt = gcur[b];
    if (cnt > BCAP) cnt = BCAP;
    const int gbase = base[b];
    const int2* pb = part + (size_t)b * BCAP;

    if (t < 512) hist[t] = 0;
    __syncthreads();
    for (int i = t; i < cnt; i += 1024) {
        int dl = (pb[i].x >> 17) & 511;
        atomicAdd(&hist[dl], 1);
    }
    __syncthreads();
    int myh = (t < 512) ? hist[t] : 0;          // this node's count
    // inclusive scan of hist[0..511]
#pragma unroll
    for (int off = 1; off < 512; off <<= 1) {
        int x = (t < 512 && t >= off) ? hist[t - off] : 0;
        __syncthreads();
        if (t < 512) hist[t] += x;
        __syncthreads();
    }
    int myexcl = (t < 512) ? (hist[t] - myh) : 0;
    if (t < 512) cur[t] = myexcl;
    __syncthreads();
    // scatter into sorted position (writes stay within this bucket's region)
    for (int i = t; i < cnt; i += 1024) {
        int2 p = pb[i];
        int dl = (p.x >> 17) & 511;
        int pos = atomicAdd(&cur[dl], 1);
        ev[(size_t)gbase + pos] = p;
    }
    __threadfence();
    __syncthreads();
    // per-node: deg = 1 + sum(ew over sorted range); dinv, rp
    if (t < 512) {
        int g = (b << BSHIFT) + t;
        if (g < n) {
            float deg = 1.f;
            for (int i = 0; i < myh; ++i)
                deg += __int_as_float(ev[(size_t)gbase + myexcl + i].y);
            dinv[g] = rsqrtf(deg);
            rp[g] = gbase + myexcl;
        }
    }
}

// in-place: {src | dl<<17, ew} -> {src, dinv[src]*ew*dinv[dst]}
__global__ void normfix(int2* __restrict__ ev, const int* __restrict__ rp,
                        const float* __restrict__ dinv, int n) {
    int g = blockIdx.x * 256 + threadIdx.x;
    if (g >= n) return;
    float dd = dinv[g];
    int s = rp[g], e = rp[g + 1];
    for (int i = s; i < e; ++i) {
        int2 p = ev[i];
        int src = p.x & 0x1FFFF;
        float norm = dinv[src] * __int_as_float(p.y) * dd;
        ev[i] = make_int2(src, __float_as_int(norm));
    }
}

// ---------------- gather (unchanged from round 4) ----------------
__global__ __launch_bounds__(256) void gather_bf(
    const int* __restrict__ rp, const int2* __restrict__ ev,
    const unsigned short* __restrict__ h,
    const float* __restrict__ dinv, const float* __restrict__ bias,
    unsigned short* __restrict__ aggr, int n) {
    int node = (int)(((size_t)blockIdx.x * 256 + threadIdx.x) >> 6);
    if (node >= n) return;
    int lane = threadIdx.x & 63;
    float di = dinv[node];
    float sl = di * di;
    unsigned int hu = *(const unsigned int*)(h + (size_t)node * 128 + lane * 2);
    float2 bv = *(const float2*)(bias + lane * 2);
    float a0x = bv.x + sl * bflo(hu), a0y = bv.y + sl * bfhi(hu);
    float a1x = 0.f, a1y = 0.f, a2x = 0.f, a2y = 0.f, a3x = 0.f, a3y = 0.f;
    int beg = rp[node], end = rp[node + 1];
    int i = beg;
    for (; i + 3 < end; i += 4) {
        int2 e0 = ev[i], e1 = ev[i + 1], e2 = ev[i + 2], e3 = ev[i + 3];
        unsigned int u0 = *(const unsigned int*)(h + (size_t)e0.x * 128 + lane * 2);
        unsigned int u1 = *(const unsigned int*)(h + (size_t)e1.x * 128 + lane * 2);
        unsigned int u2 = *(const unsigned int*)(h + (size_t)e2.x * 128 + lane * 2);
        unsigned int u3 = *(const unsigned int*)(h + (size_t)e3.x * 128 + lane * 2);
        float n0 = __int_as_float(e0.y), n1 = __int_as_float(e1.y);
        float n2 = __int_as_float(e2.y), n3 = __int_as_float(e3.y);
        a0x += n0 * bflo(u0); a0y += n0 * bfhi(u0);
        a1x += n1 * bflo(u1); a1y += n1 * bfhi(u1);
        a2x += n2 * bflo(u2); a2y += n2 * bfhi(u2);
        a3x += n3 * bflo(u3); a3y += n3 * bfhi(u3);
    }
    for (; i < end; ++i) {
        int2 e0 = ev[i];
        unsigned int u0 = *(const unsigned int*)(h + (size_t)e0.x * 128 + lane * 2);
        float n0 = __int_as_float(e0.y);
        a0x += n0 * bflo(u0); a0y += n0 * bfhi(u0);
    }
    float ox = frelu((a0x + a1x) + (a2x + a3x));
    float oy = frelu((a0y + a1y) + (a2y + a3y));
    unsigned int o = (unsigned int)f2bf(ox) | ((unsigned int)f2bf(oy) << 16);
    *(unsigned int*)(aggr + (size_t)node * 128 + lane * 2) = o;
}

// ---------------- bf16 MFMA GEMM (unchanged) ----------------
template<int K, int RELU, int EPI>
__global__ __launch_bounds__(256, 2) void gemm_bf(
    const unsigned short* __restrict__ A, const unsigned short* __restrict__ Wt,
    const float* __restrict__ bias, void* __restrict__ Cout,
    int M, int nrows, float* __restrict__ xs) {
    constexpr int BM = 128, BN = 64, BK = 64;
    __shared__ unsigned short As[BM][BK + 8];
    __shared__ unsigned short Bs[BN][BK + 8];

    const int tid  = threadIdx.x;
    const int wid  = tid >> 6;
    const int lane = tid & 63;
    const int wm   = (wid >> 1) * 64;
    const int wn   = (wid & 1) * 32;
    const int row0 = blockIdx.x * BM;
    const int col0 = blockIdx.y * BN;
    const int lr   = lane & 15;
    const int lk   = (lane >> 4) * 8;

    f32x4 acc[4][2] = {};

    for (int k0 = 0; k0 < K; k0 += BK) {
#pragma unroll
        for (int it = 0; it < 4; ++it) {
            int f = tid + it * 256;
            int r = f >> 3, g = f & 7;
            int grow = row0 + r;
            if (grow >= nrows) grow = nrows - 1;
            bf16x8 v = *(const bf16x8*)(A + (size_t)grow * K + k0 + g * 8);
            *(bf16x8*)&As[r][g * 8] = v;
        }
#pragma unroll
        for (int it = 0; it < 2; ++it) {
            int f = tid + it * 256;
            int nidx = f >> 3, g = f & 7;
            bf16x8 v = *(const bf16x8*)(Wt + (size_t)(col0 + nidx) * K + k0 + g * 8);
            *(bf16x8*)&Bs[nidx][g * 8] = v;
        }
        __syncthreads();
#pragma unroll
        for (int kk = 0; kk < 2; ++kk) {
            bf16x8 af[4], bfv[2];
#pragma unroll
            for (int mi = 0; mi < 4; ++mi)
                af[mi] = *(const bf16x8*)&As[wm + 16 * mi + lr][kk * 32 + lk];
#pragma unroll
            for (int ni = 0; ni < 2; ++ni)
                bfv[ni] = *(const bf16x8*)&Bs[wn + 16 * ni + lr][kk * 32 + lk];
#pragma unroll
            for (int mi = 0; mi < 4; ++mi)
#pragma unroll
                for (int ni = 0; ni < 2; ++ni)
                    acc[mi][ni] = __builtin_amdgcn_mfma_f32_16x16x32_bf16(
                        af[mi], bfv[ni], acc[mi][ni], 0, 0, 0);
        }
        __syncthreads();
    }

    const int dr0 = (lane >> 4) * 4;
#pragma unroll
    for (int ni = 0; ni < 2; ++ni) {
        int col = col0 + wn + 16 * ni + lr;
        float bv = bias ? bias[col] : 0.f;
#pragma unroll
        for (int mi = 0; mi < 4; ++mi) {
#pragma unroll
            for (int r = 0; r < 4; ++r) {
                int grow = row0 + wm + 16 * mi + dr0 + r;
                if (grow >= nrows) continue;
                float v = acc[mi][ni][r] + bv;
                if (RELU) v = frelu(v);
                if (EPI == 0) {
                    ((unsigned short*)Cout)[(size_t)grow * M + col] = f2bf(v);
                } else {
                    ((float*)Cout)[(size_t)grow * M + col] = v;
                    if (EPI == 2) xs[(size_t)grow * 64 + col] += v;
                }
            }
        }
    }
}

// ---------------------------------------------------------------------------
extern "C" void kernel_launch(void* const* d_in, const int* in_sizes, int n_in,
                              void* d_out, int out_size, void* d_ws, size_t ws_size,
                              hipStream_t stream) {
    (void)n_in; (void)out_size; (void)ws_size;
    const float* X = (const float*)d_in[0];
    const int N = in_sizes[0] / 128;

    const float* fc1_w1 = (const float*)d_in[19];
    const float* fc1_b1 = (const float*)d_in[20];
    const float* fc1_w2 = (const float*)d_in[21];
    const float* fc1_b2 = (const float*)d_in[22];
    const float* fc1_w3 = (const float*)d_in[23];
    const float* fc1_b3 = (const float*)d_in[24];
    const float* fc2_w1 = (const float*)d_in[25];
    const float* fc2_b1 = (const float*)d_in[26];
    const float* fc2_w2 = (const float*)d_in[27];
    const float* fc2_b2 = (const float*)d_in[28];
    const float* fc2_w3 = (const float*)d_in[29];
    const float* fc2_b3 = (const float*)d_in[30];

    float* out = (float*)d_out;
    float* Xs  = out;  // slot 0

    // ---- workspace layout ----
    char* base = (char*)d_ws;
    const size_t Npad = (((size_t)N + 255) / 256) * 256;
    float*          dinv  = (float*)base;                 base += Npad * 4;
    unsigned short* Xbf   = (unsigned short*)base;        base += (size_t)N * 128 * 2;
    unsigned short* t1bf  = (unsigned short*)base;        base += (size_t)N * 256 * 2;  // CSR arena alias
    unsigned short* t2bf  = (unsigned short*)base;        base += (size_t)N * 128 * 2;
    unsigned short* aggbf = (unsigned short*)base;        base += (size_t)N * 128 * 2;
    unsigned short* wtbuf = (unsigned short*)base;

    unsigned short* fc1w1t = wtbuf;
    unsigned short* fc1w2t = fc1w1t + 32768;
    unsigned short* fc1w3t = fc1w2t + 32768;
    unsigned short* fc2w1t = fc1w3t + 8192;
    unsigned short* fc2w2t = fc2w1t + 32768;
    unsigned short* fc2w3t = fc2w2t + 32768;
    unsigned short* gwt    = fc2w3t + 8192;

    const dim3 blk(256);
    const int GR = (N + 127) / 128;
    const int NB = (N + 255) / 256;
    const int GWB = (int)(((size_t)N * 64 + 255) / 256);

    // ---- one-time conversions ----
    xconv<<<(N * 32 + 255) / 256, blk, 0, stream>>>(X, Xbf, N * 32);
    wtrans<<<(128 * 256 + 255) / 256, blk, 0, stream>>>(fc1_w1, fc1w1t, 128, 256);
    wtrans<<<(256 * 128 + 255) / 256, blk, 0, stream>>>(fc1_w2, fc1w2t, 256, 128);
    wtrans<<<(128 * 64 + 255) / 256, blk, 0, stream>>>(fc1_w3, fc1w3t, 128, 64);
    wtrans<<<(128 * 256 + 255) / 256, blk, 0, stream>>>(fc2_w1, fc2w1t, 128, 256);
    wtrans<<<(256 * 128 + 255) / 256, blk, 0, stream>>>(fc2_w2, fc2w2t, 256, 128);
    wtrans<<<(128 * 64 + 255) / 256, blk, 0, stream>>>(fc2_w3, fc2w3t, 128, 64);
    for (int g = 0; g < 3; ++g) {
        wtrans<<<(128 * 128 + 255) / 256, blk, 0, stream>>>(
            (const float*)d_in[3 + 6 * g], gwt + g * 32768, 128, 128);
        wtrans<<<(128 * 128 + 255) / 256, blk, 0, stream>>>(
            (const float*)d_in[5 + 6 * g], gwt + g * 32768 + 16384, 128, 128);
    }

    // ---- X0 = fc1(X) -> Xs ----
    gemm_bf<128, 1, 0><<<dim3(GR, 4), blk, 0, stream>>>(Xbf, fc1w1t, fc1_b1, t1bf, 256, N, nullptr);
    gemm_bf<256, 1, 0><<<dim3(GR, 2), blk, 0, stream>>>(t1bf, fc1w2t, fc1_b2, t2bf, 128, N, nullptr);
    gemm_bf<128, 1, 1><<<dim3(GR, 1), blk, 0, stream>>>(t2bf, fc1w3t, fc1_b3, Xs, 64, N, nullptr);

    // ---- graphs ----
    for (int g = 0; g < 3; ++g) {
        const int*   ei  = (const int*)d_in[1 + 6 * g];
        const int    E   = in_sizes[1 + 6 * g] / 2;
        const int*   srp = ei;
        const int*   dsp = ei + E;
        const float* ew  = (const float*)d_in[2 + 6 * g];
        const float* b1  = (const float*)d_in[4 + 6 * g];
        const float* b2  = (const float*)d_in[6 + 6 * g];
        unsigned short* w1t = gwt + g * 32768;
        unsigned short* w2t = w1t + 16384;

        // CSR arena aliases t1bf (dead during conv phase). int2 arrays first (8B align).
        int2* part  = (int2*)t1bf;                   // NBUCK * BCAP
        int2* ev    = part + (size_t)NBUCK * BCAP;   // E
        int*  rpn   = (int*)(ev + E);                // N+1
        int*  gcur  = rpn + (N + 1);                 // NBUCK
        int*  bbase = gcur + NBUCK;                  // NBUCK

        zero_small<<<1, blk, 0, stream>>>(gcur, NBUCK);
        part_k<<<(E + 4095) / 4096, blk, 0, stream>>>(srp, dsp, ew, gcur, part, E);
        scanB<<<1, blk, 0, stream>>>(gcur, bbase, rpn, N, E);
        sort_k<<<NBUCK, 1024, 0, stream>>>(part, gcur, bbase, ev, rpn, dinv, N);
        normfix<<<NB, blk, 0, stream>>>(ev, rpn, dinv, N);

        // conv1 + conv2 (gather applies bias+relu, bf16)
        gemm_bf<128, 0, 0><<<dim3(GR, 2), blk, 0, stream>>>(Xbf, w1t, nullptr, t2bf, 128, N, nullptr);
        gather_bf<<<GWB, blk, 0, stream>>>(rpn, ev, t2bf, dinv, b1, aggbf, N);
        gemm_bf<128, 0, 0><<<dim3(GR, 2), blk, 0, stream>>>(aggbf, w2t, nullptr, t2bf, 128, N, nullptr);
        gather_bf<<<GWB, blk, 0, stream>>>(rpn, ev, t2bf, dinv, b2, aggbf, N);

        // fc2 head
        gemm_bf<128, 1, 0><<<dim3(GR, 4), blk, 0, stream>>>(aggbf, fc2w1t, fc2_b1, t1bf, 256, N, nullptr);
        gemm_bf<256, 1, 0><<<dim3(GR, 2), blk, 0, stream>>>(t1bf, fc2w2t, fc2_b2, t2bf, 128, N, nullptr);
        gemm_bf<128, 1, 2><<<dim3(GR, 1), blk, 0, stream>>>(
            t2bf, fc2w3t, fc2_b3, out + (size_t)(1 + g) * N * 64, 64, N, Xs);
    }
}